// Round 5
// baseline (1853.103 us; speedup 1.0000x reference)
//
#include <hip/hip_runtime.h>

constexpr int BB   = 16;
constexpr int NN   = 2000000;
constexpr int NPIX = 3072;
constexpr int NOUT = 100;
constexpr int NBX_POOL = 128;     // pool blocks per batch (2048 total, 8/CU)
constexpr float EPS = 1e-5f;

__device__ __forceinline__ float gatomic_add(float* p, float v) {
  return __hip_atomic_fetch_add(p, v, __ATOMIC_RELAXED, __HIP_MEMORY_SCOPE_AGENT);
}
__device__ __forceinline__ void gatomic_add_u64(unsigned long long* p, unsigned long long v) {
  __hip_atomic_fetch_add(p, v, __ATOMIC_RELAXED, __HIP_MEMORY_SCOPE_AGENT);
}

// ---- Kernel 1: segment pooling via DIRECT GLOBAL u64 atomics (IF$-side RMW) ---
// enc = (1<<44) + round((v+16)*2^20); count bits 44..63, biased sum low 44.
// Per-(b,pix) bin: ~651 elems avg; sum field max ~651*32*2^20 ≈ 2.2e10 << 2^44.
__global__ __launch_bounds__(256) void k_pool(const float* __restrict__ x,
                                              const int* __restrict__ pix,
                                              unsigned long long* __restrict__ gbins) {
  const int b = blockIdx.y;
  const float4* xv = (const float4*)(x + ((size_t)b * 3 + 2) * NN);
  const int4*   pv = (const int4*)(pix + (size_t)b * NN);
  unsigned long long* bb = gbins + (size_t)b * NPIX;
  const int nv = NN / 4;
  for (int i = blockIdx.x * 256 + threadIdx.x; i < nv; i += NBX_POOL * 256) {
    float4 v = xv[i];
    int4   p = pv[i];
    unsigned long long e0 = (1ull << 44) + (unsigned long long)__float2uint_rn((v.x + 16.f) * 1048576.f);
    unsigned long long e1 = (1ull << 44) + (unsigned long long)__float2uint_rn((v.y + 16.f) * 1048576.f);
    unsigned long long e2 = (1ull << 44) + (unsigned long long)__float2uint_rn((v.z + 16.f) * 1048576.f);
    unsigned long long e3 = (1ull << 44) + (unsigned long long)__float2uint_rn((v.w + 16.f) * 1048576.f);
    gatomic_add_u64(&bb[p.x], e0);
    gatomic_add_u64(&bb[p.y], e1);
    gatomic_add_u64(&bb[p.z], e2);
    gatomic_add_u64(&bb[p.w], e3);
  }
}

// ---- Kernel 2: extract sparse structure of adj (<=8 nnz/row) ------------------
__global__ __launch_bounds__(256) void k_extract(const float* __restrict__ adj,
                                                 int* __restrict__ cols,
                                                 float* __restrict__ vals,
                                                 int* __restrict__ rc) {
  const int p = blockIdx.x;
  __shared__ int cnt;
  if (threadIdx.x == 0) cnt = 0;
  __syncthreads();
  const float4* row = (const float4*)(adj + (size_t)p * NPIX);
  for (int i = threadIdx.x; i < NPIX / 4; i += 256) {
    float4 a = row[i];
    if (a.x != 0.f) { int s = atomicAdd(&cnt, 1); if (s < 8) { cols[p*8+s] = i*4+0; vals[p*8+s] = a.x; } }
    if (a.y != 0.f) { int s = atomicAdd(&cnt, 1); if (s < 8) { cols[p*8+s] = i*4+1; vals[p*8+s] = a.y; } }
    if (a.z != 0.f) { int s = atomicAdd(&cnt, 1); if (s < 8) { cols[p*8+s] = i*4+2; vals[p*8+s] = a.z; } }
    if (a.w != 0.f) { int s = atomicAdd(&cnt, 1); if (s < 8) { cols[p*8+s] = i*4+3; vals[p*8+s] = a.w; } }
  }
  __syncthreads();
  if (threadIdx.x == 0) rc[p] = min(cnt, 8);
}

// ---- Kernel 3: conv1 (in-features = 1): decode bins + sparse agg + W1 + LN ----
__global__ __launch_bounds__(256) void k_conv1(const unsigned long long* __restrict__ gbins,
                                               const int* __restrict__ cols,
                                               const float* __restrict__ vals,
                                               const int* __restrict__ rc,
                                               const float* __restrict__ W1,
                                               const float* __restrict__ b1,
                                               const float* __restrict__ g1,
                                               const float* __restrict__ be1,
                                               float* __restrict__ h1) {
  const int lane = threadIdx.x & 63;
  const int wid  = threadIdx.x >> 6;
  const int p = blockIdx.x * 4 + wid;
  const int b = blockIdx.y;
  const int n = rc[p];
  float contrib = 0.f;
  if (lane < n) {
    const int   q = cols[p*8 + lane];
    const float w = vals[p*8 + lane];
    const unsigned long long pb = gbins[(size_t)b * NPIX + q];
    const float ct = (float)(unsigned int)(pb >> 44);
    const double sf = (double)(pb & ((1ull << 44) - 1));
    const float c = (ct == 0.f) ? 1.f : ct;
    const float mean = (float)(sf * (1.0 / 1048576.0) - 16.0 * (double)ct) / c;
    contrib = w * mean;
  }
  #pragma unroll
  for (int d = 1; d < 64; d <<= 1) contrib += __shfl_xor(contrib, d);
  const float agg = contrib;
  const float o = agg * W1[lane] + b1[lane];
  float ssum = o, ssq = o * o;
  #pragma unroll
  for (int d = 1; d < 64; d <<= 1) { ssum += __shfl_xor(ssum, d); ssq += __shfl_xor(ssq, d); }
  const float mu  = ssum * (1.f / 64.f);
  const float var = ssq * (1.f / 64.f) - mu * mu;
  float y = (o - mu) * rsqrtf(var + EPS) * g1[lane] + be1[lane];
  y = fmaxf(y, 0.f);
  h1[((size_t)b * NPIX + p) * 64 + lane] = y;
}

// ---- Kernel 4: conv2 + fused pixel-mean partial ------------------------------
__global__ __launch_bounds__(256) void k_conv2(const float* __restrict__ h1,
                                               const int* __restrict__ cols,
                                               const float* __restrict__ vals,
                                               const int* __restrict__ rc,
                                               const float* __restrict__ W2,
                                               const float* __restrict__ b2,
                                               const float* __restrict__ g2,
                                               const float* __restrict__ be2,
                                               float* __restrict__ h2,
                                               float* __restrict__ msum) {
  __shared__ float Bs[64 * 64];
  __shared__ float Ast[64 * 68];
  __shared__ float colsum[64];
  const int b  = blockIdx.y;
  const int p0 = blockIdx.x * 64;
  const int tid = threadIdx.x;
  if (tid < 64) colsum[tid] = 0.f;
  for (int i = tid; i < 4096; i += 256) Bs[i] = W2[i];
  {
    const int r = tid >> 2;
    const int q = tid & 3;
    const int p = p0 + r;
    const int n = rc[p];
    float a[16];
    #pragma unroll
    for (int j = 0; j < 16; ++j) a[j] = 0.f;
    const float* hb = h1 + (size_t)b * NPIX * 64;
    for (int k = 0; k < n; ++k) {
      const int   qq = cols[p*8 + k];
      const float w  = vals[p*8 + k];
      const float4* src = (const float4*)(hb + (size_t)qq * 64 + q * 16);
      float4 s0 = src[0], s1 = src[1], s2 = src[2], s3 = src[3];
      a[0]  += w * s0.x; a[1]  += w * s0.y; a[2]  += w * s0.z; a[3]  += w * s0.w;
      a[4]  += w * s1.x; a[5]  += w * s1.y; a[6]  += w * s1.z; a[7]  += w * s1.w;
      a[8]  += w * s2.x; a[9]  += w * s2.y; a[10] += w * s2.z; a[11] += w * s2.w;
      a[12] += w * s3.x; a[13] += w * s3.y; a[14] += w * s3.z; a[15] += w * s3.w;
    }
    #pragma unroll
    for (int j = 0; j < 16; ++j) Ast[(q * 16 + j) * 68 + r] = a[j];
  }
  __syncthreads();
  const int lane = tid & 63;
  const int w    = tid >> 6;
  const int rt   = lane >> 4;
  const int ct   = lane & 15;
  const int r0   = w * 16 + rt * 4;
  const int c0   = ct * 4;
  float acc[4][4];
  #pragma unroll
  for (int i = 0; i < 4; ++i)
    #pragma unroll
    for (int j = 0; j < 4; ++j) acc[i][j] = 0.f;
  #pragma unroll 4
  for (int g = 0; g < 64; ++g) {
    const float4 av = *(const float4*)&Ast[g * 68 + r0];
    const float4 bv = *(const float4*)&Bs[g * 64 + c0];
    acc[0][0] += av.x * bv.x; acc[0][1] += av.x * bv.y; acc[0][2] += av.x * bv.z; acc[0][3] += av.x * bv.w;
    acc[1][0] += av.y * bv.x; acc[1][1] += av.y * bv.y; acc[1][2] += av.y * bv.z; acc[1][3] += av.y * bv.w;
    acc[2][0] += av.z * bv.x; acc[2][1] += av.z * bv.y; acc[2][2] += av.z * bv.z; acc[2][3] += av.z * bv.w;
    acc[3][0] += av.w * bv.x; acc[3][1] += av.w * bv.y; acc[3][2] += av.w * bv.z; acc[3][3] += av.w * bv.w;
  }
  const float4 b2v = *(const float4*)&b2[c0];
  const float4 g2v = *(const float4*)&g2[c0];
  const float4 bev = *(const float4*)&be2[c0];
  float* hb2 = h2 + ((size_t)b * NPIX + p0) * 64;
  float cs0 = 0.f, cs1 = 0.f, cs2 = 0.f, cs3 = 0.f;
  #pragma unroll
  for (int i = 0; i < 4; ++i) {
    float o0 = acc[i][0] + b2v.x, o1 = acc[i][1] + b2v.y;
    float o2 = acc[i][2] + b2v.z, o3 = acc[i][3] + b2v.w;
    float rs = o0 + o1 + o2 + o3;
    float rq = o0*o0 + o1*o1 + o2*o2 + o3*o3;
    #pragma unroll
    for (int d = 1; d < 16; d <<= 1) { rs += __shfl_xor(rs, d); rq += __shfl_xor(rq, d); }
    const float mu  = rs * (1.f / 64.f);
    const float var = rq * (1.f / 64.f) - mu * mu;
    const float inv = rsqrtf(var + EPS);
    float4 y;
    y.x = fmaxf((o0 - mu) * inv * g2v.x + bev.x, 0.f);
    y.y = fmaxf((o1 - mu) * inv * g2v.y + bev.y, 0.f);
    y.z = fmaxf((o2 - mu) * inv * g2v.z + bev.z, 0.f);
    y.w = fmaxf((o3 - mu) * inv * g2v.w + bev.w, 0.f);
    *(float4*)&hb2[(size_t)(r0 + i) * 64 + c0] = y;
    cs0 += y.x; cs1 += y.y; cs2 += y.z; cs3 += y.w;
  }
  atomicAdd(&colsum[c0+0], cs0);
  atomicAdd(&colsum[c0+1], cs1);
  atomicAdd(&colsum[c0+2], cs2);
  atomicAdd(&colsum[c0+3], cs3);
  __syncthreads();
  if (tid < 64) gatomic_add(&msum[b * 64 + tid], colsum[tid]);
}

// ---- Kernel 5: head ----------------------------------------------------------
__global__ __launch_bounds__(128) void k_head(const float* __restrict__ msum,
                                              const float* __restrict__ Wr,
                                              const float* __restrict__ br,
                                              const float* __restrict__ scale,
                                              float* __restrict__ out) {
  const int b = blockIdx.x;
  __shared__ float hm[64];
  if (threadIdx.x < 64) hm[threadIdx.x] = msum[b * 64 + threadIdx.x] * (1.f / NPIX);
  __syncthreads();
  const int o = threadIdx.x;
  if (o < NOUT) {
    float a = br[o];
    #pragma unroll 8
    for (int f = 0; f < 64; ++f) a += hm[f] * Wr[f * NOUT + o];
    out[b * NOUT + o] = a * scale[0];
  }
}

extern "C" void kernel_launch(void* const* d_in, const int* in_sizes, int n_in,
                              void* d_out, int out_size, void* d_ws, size_t ws_size,
                              hipStream_t stream) {
  const float* x    = (const float*)d_in[0];
  const int*   pix  = (const int*)d_in[1];
  const float* adj  = (const float*)d_in[2];
  const float* W1   = (const float*)d_in[3];
  const float* b1   = (const float*)d_in[4];
  const float* g1   = (const float*)d_in[5];
  const float* be1  = (const float*)d_in[6];
  const float* W2   = (const float*)d_in[7];
  const float* b2   = (const float*)d_in[8];
  const float* g2   = (const float*)d_in[9];
  const float* be2  = (const float*)d_in[10];
  const float* Wr   = (const float*)d_in[11];
  const float* br   = (const float*)d_in[12];
  const float* scale= (const float*)d_in[13];
  float* out = (float*)d_out;
  float* ws  = (float*)d_ws;

  // workspace layout (float-offset units); gbins u64 first (8B aligned)
  unsigned long long* gbins = (unsigned long long*)ws;  // 49152 u64 = 98304 floats
  float* msum = ws + 98304;             // 1024
  int*   cols = (int*)(ws + 99328);     // 24576
  float* vals = ws + 123904;            // 24576
  int*   rc   = (int*)(ws + 148480);    // 3072
  float* h1   = ws + 151552;            // 3145728
  float* h2   = h1 + 3145728;           // 3145728 (end: 6443008 floats = 25.8 MB)

  // zero gbins + msum (397 KB; graph-capture-safe async memset)
  hipMemsetAsync(ws, 0, (size_t)(98304 + 1024) * sizeof(float), stream);

  k_pool   <<<dim3(NBX_POOL, BB), 256, 0, stream>>>(x, pix, gbins);
  k_extract<<<NPIX,               256, 0, stream>>>(adj, cols, vals, rc);
  k_conv1  <<<dim3(NPIX/4, BB),   256, 0, stream>>>(gbins, cols, vals, rc,
                                                    W1, b1, g1, be1, h1);
  k_conv2  <<<dim3(NPIX/64, BB),  256, 0, stream>>>(h1, cols, vals, rc,
                                                    W2, b2, g2, be2, h2, msum);
  k_head   <<<BB,                 128, 0, stream>>>(msum, Wr, br, scale, out);
}